// Round 2
// baseline (346.568 us; speedup 1.0000x reference)
//
#include <hip/hip_runtime.h>

#define NBLOCKS 2048
#define NTHREADS 256
#define UNROLL 8   // 8 vec4 per stream per chunk iteration

typedef float vfloat4 __attribute__((ext_vector_type(4)));

#if defined(__has_builtin)
#  if __has_builtin(__builtin_amdgcn_sched_barrier)
#    define SCHED_FENCE() __builtin_amdgcn_sched_barrier(0)
#  endif
#endif
#ifndef SCHED_FENCE
#  define SCHED_FENCE()
#endif

// Single fused kernel: streaming pass (byte-identical main loop to the
// 247.2 µs version) + last-block-done final reduction. Removes the second
// kernel dispatch node and its dependency gap from the graph; a 4-byte
// memset on the ticket counter replaces it (cheaper node).
//
// Cross-XCD correctness: partial[] stores and the final reads use
// agent-scope atomics, and the ticket fetch_add is ACQ_REL agent-scope —
// this gives the release/acquire chain the non-coherent per-XCD L2s need
// (guide §6 G16). Kernel-boundary flush is no longer available, so plain
// loads/stores would be unsafe here.
__global__ __launch_bounds__(NTHREADS, 4) void l1_fused_kernel(
    const vfloat4* __restrict__ a, const vfloat4* __restrict__ b,
    const float* __restrict__ af, const float* __restrict__ bf,
    float* __restrict__ partial, unsigned* __restrict__ counter,
    float* __restrict__ out, long n4, long n_total, float inv_n) {
    const int tid = threadIdx.x;
    const long chunk = (long)NTHREADS * UNROLL;   // 2048 vec4 (32 KB) per block-chunk
    const long nchunks = n4 / chunk;

    float acc[UNROLL];
    #pragma unroll
    for (int j = 0; j < UNROLL; ++j) acc[j] = 0.f;

    for (long c = blockIdx.x; c < nchunks; c += NBLOCKS) {
        const long base = c * chunk + tid;
        vfloat4 xs[UNROLL], ys[UNROLL];
        // Nontemporal: nt policy bypasses L1 allocation (deeper L2 queues),
        // avoids thrashing the exactly-256MiB L3 working set.
        #pragma unroll
        for (int j = 0; j < UNROLL; ++j)
            xs[j] = __builtin_nontemporal_load(&a[base + j * NTHREADS]);
        #pragma unroll
        for (int j = 0; j < UNROLL; ++j)
            ys[j] = __builtin_nontemporal_load(&b[base + j * NTHREADS]);
        SCHED_FENCE();
        #pragma unroll
        for (int j = 0; j < UNROLL; ++j) {
            vfloat4 d = xs[j] - ys[j];
            acc[j] += fabsf(d.x) + fabsf(d.y) + fabsf(d.z) + fabsf(d.w);
        }
    }

    // remainder vec4s not covered by full chunks (none for this shape)
    float racc = 0.f;
    const long gid = (long)blockIdx.x * NTHREADS + tid;
    const long tthreads = (long)NBLOCKS * NTHREADS;
    for (long i = nchunks * chunk + gid; i < n4; i += tthreads) {
        vfloat4 x = a[i], y = b[i];
        racc += fabsf(x.x - y.x) + fabsf(x.y - y.y)
              + fabsf(x.z - y.z) + fabsf(x.w - y.w);
    }
    // scalar tail for n % 4 (none for this shape)
    for (long e = n4 * 4 + gid; e < n_total; e += tthreads)
        racc += fabsf(af[e] - bf[e]);

    float acc_total = ((acc[0] + acc[1]) + (acc[2] + acc[3]))
                    + ((acc[4] + acc[5]) + (acc[6] + acc[7])) + racc;

    #pragma unroll
    for (int off = 32; off > 0; off >>= 1)
        acc_total += __shfl_down(acc_total, off, 64);

    __shared__ float smem[NTHREADS / 64];
    __shared__ unsigned last_flag;
    const int wave = tid >> 6;
    const int lane = tid & 63;
    if (lane == 0) smem[wave] = acc_total;
    __syncthreads();

    if (tid == 0) {
        float s = 0.f;
        #pragma unroll
        for (int w = 0; w < NTHREADS / 64; ++w) s += smem[w];
        // Publish partial (agent scope: write-through past the XCD L2),
        // then take a ticket. ACQ_REL: release our partial, acquire all
        // earlier blocks' partials if we're last.
        __hip_atomic_store(&partial[blockIdx.x], s,
                           __ATOMIC_RELAXED, __HIP_MEMORY_SCOPE_AGENT);
        unsigned old = __hip_atomic_fetch_add(counter, 1u,
                           __ATOMIC_ACQ_REL, __HIP_MEMORY_SCOPE_AGENT);
        last_flag = (old == (unsigned)(NBLOCKS - 1)) ? 1u : 0u;
    }
    __syncthreads();   // broadcasts last_flag; orders smem reuse below

    if (last_flag) {
        // Last block standing: fold the 2048 partials (8 KB). Agent-scope
        // loads read from the device-coherent point (other XCDs' data).
        float s = 0.f;
        #pragma unroll
        for (int j = 0; j < NBLOCKS / NTHREADS; ++j)
            s += __hip_atomic_load(&partial[tid + j * NTHREADS],
                                   __ATOMIC_RELAXED, __HIP_MEMORY_SCOPE_AGENT);
        #pragma unroll
        for (int off = 32; off > 0; off >>= 1)
            s += __shfl_down(s, off, 64);
        if (lane == 0) smem[wave] = s;
        __syncthreads();
        if (tid == 0) {
            float t = 0.f;
            #pragma unroll
            for (int w = 0; w < NTHREADS / 64; ++w) t += smem[w];
            out[0] = t * inv_n;   // full overwrite of poisoned d_out
        }
    }
}

extern "C" void kernel_launch(void* const* d_in, const int* in_sizes, int n_in,
                              void* d_out, int out_size, void* d_ws, size_t ws_size,
                              hipStream_t stream) {
    const float* yhat = (const float*)d_in[0];
    const float* y    = (const float*)d_in[1];
    float* out = (float*)d_out;

    // ws layout: [0..3] ticket counter, [256..256+8K) partials
    // (separate cachelines so counter RMW traffic doesn't collide with
    // block 0's partial line).
    unsigned* counter = (unsigned*)d_ws;
    float* partial = (float*)((char*)d_ws + 256);

    long n = (long)in_sizes[0];
    long n4 = n / 4;
    float inv_n = 1.0f / (float)n;

    // Ticket counter must start at 0 every replay; ws is poisoned by the
    // harness, so zero it explicitly (4-byte fill node — cheaper than the
    // reduce-kernel node it replaces).
    (void)hipMemsetAsync(counter, 0, sizeof(unsigned), stream);
    l1_fused_kernel<<<NBLOCKS, NTHREADS, 0, stream>>>(
        (const vfloat4*)yhat, (const vfloat4*)y, yhat, y,
        partial, counter, out, n4, n, inv_n);
}

// Round 3
// 247.753 us; speedup vs baseline: 1.3988x; 1.3988x over previous
//
#include <hip/hip_runtime.h>

#define NBLOCKS 2048
#define NTHREADS 256
#define UNROLL 8   // 8 vec4 per stream per chunk iteration

typedef float vfloat4 __attribute__((ext_vector_type(4)));

#if defined(__has_builtin)
#  if __has_builtin(__builtin_amdgcn_sched_barrier)
#    define SCHED_FENCE() __builtin_amdgcn_sched_barrier(0)
#  endif
#endif
#ifndef SCHED_FENCE
#  define SCHED_FENCE()
#endif

// Streaming pass: proven 247.2 µs structure (round 1). Block result goes to
// a distinct partial[blockIdx.x] slot (plain store). Final reduction is a
// separate kernel — kernel-boundary ordering on the stream handles cross-XCD
// visibility for free. DO NOT fuse with a grid-wide ticket: per-block
// agent-scope ACQ_REL atomics emit buffer_inv (XCD-L2 invalidate) per block,
// which cost +99 µs when tried (round 2, 145 µs kernel @ 920 GB/s).
__global__ __launch_bounds__(NTHREADS, 4) void l1_partial_kernel(
    const vfloat4* __restrict__ a, const vfloat4* __restrict__ b,
    const float* __restrict__ af, const float* __restrict__ bf,
    float* __restrict__ partial, long n4, long n_total) {
    const int tid = threadIdx.x;
    const long chunk = (long)NTHREADS * UNROLL;   // 2048 vec4 (32 KB) per block-chunk
    const long nchunks = n4 / chunk;

    float acc[UNROLL];
    #pragma unroll
    for (int j = 0; j < UNROLL; ++j) acc[j] = 0.f;

    for (long c = blockIdx.x; c < nchunks; c += NBLOCKS) {
        const long base = c * chunk + tid;
        vfloat4 xs[UNROLL], ys[UNROLL];
        // Nontemporal: nt policy bypasses L1 allocation (deeper L2 queues),
        // avoids thrashing the exactly-256MiB L3 working set.
        #pragma unroll
        for (int j = 0; j < UNROLL; ++j)
            xs[j] = __builtin_nontemporal_load(&a[base + j * NTHREADS]);
        #pragma unroll
        for (int j = 0; j < UNROLL; ++j)
            ys[j] = __builtin_nontemporal_load(&b[base + j * NTHREADS]);
        SCHED_FENCE();
        #pragma unroll
        for (int j = 0; j < UNROLL; ++j) {
            vfloat4 d = xs[j] - ys[j];
            acc[j] += fabsf(d.x) + fabsf(d.y) + fabsf(d.z) + fabsf(d.w);
        }
    }

    // remainder vec4s not covered by full chunks (none for this shape)
    float racc = 0.f;
    const long gid = (long)blockIdx.x * NTHREADS + tid;
    const long tthreads = (long)NBLOCKS * NTHREADS;
    for (long i = nchunks * chunk + gid; i < n4; i += tthreads) {
        vfloat4 x = a[i], y = b[i];
        racc += fabsf(x.x - y.x) + fabsf(x.y - y.y)
              + fabsf(x.z - y.z) + fabsf(x.w - y.w);
    }
    // scalar tail for n % 4 (none for this shape)
    for (long e = n4 * 4 + gid; e < n_total; e += tthreads)
        racc += fabsf(af[e] - bf[e]);

    float acc_total = ((acc[0] + acc[1]) + (acc[2] + acc[3]))
                    + ((acc[4] + acc[5]) + (acc[6] + acc[7])) + racc;

    #pragma unroll
    for (int off = 32; off > 0; off >>= 1)
        acc_total += __shfl_down(acc_total, off, 64);

    __shared__ float smem[NTHREADS / 64];
    int wave = tid >> 6;
    int lane = tid & 63;
    if (lane == 0) smem[wave] = acc_total;
    __syncthreads();
    if (tid == 0) {
        float s = 0.f;
        #pragma unroll
        for (int w = 0; w < NTHREADS / 64; ++w) s += smem[w];
        partial[blockIdx.x] = s;   // distinct address per block — no atomic, no contention
    }
}

// Tiny reduce: 1 block folds the 2048 partials (8 KB, L2-hot from the main
// kernel) and writes the final mean. Kernel-boundary ordering on the stream
// makes the partials coherent device-wide (no fences needed).
__global__ __launch_bounds__(NTHREADS, 1) void l1_reduce_kernel(
    const float* __restrict__ partial, float* __restrict__ out, float inv_n) {
    const int tid = threadIdx.x;
    float s = 0.f;
    #pragma unroll
    for (int j = 0; j < NBLOCKS / NTHREADS; ++j)
        s += partial[tid + j * NTHREADS];
    #pragma unroll
    for (int off = 32; off > 0; off >>= 1)
        s += __shfl_down(s, off, 64);
    __shared__ float smem[NTHREADS / 64];
    int wave = tid >> 6;
    int lane = tid & 63;
    if (lane == 0) smem[wave] = s;
    __syncthreads();
    if (tid == 0) {
        float t = 0.f;
        #pragma unroll
        for (int w = 0; w < NTHREADS / 64; ++w) t += smem[w];
        out[0] = t * inv_n;   // full overwrite — poisoned d_out needs no memset
    }
}

extern "C" void kernel_launch(void* const* d_in, const int* in_sizes, int n_in,
                              void* d_out, int out_size, void* d_ws, size_t ws_size,
                              hipStream_t stream) {
    const float* yhat = (const float*)d_in[0];
    const float* y    = (const float*)d_in[1];
    float* out = (float*)d_out;
    float* partial = (float*)d_ws;   // 2048 floats = 8 KB of workspace

    long n = (long)in_sizes[0];
    long n4 = n / 4;
    float inv_n = 1.0f / (float)n;

    l1_partial_kernel<<<NBLOCKS, NTHREADS, 0, stream>>>(
        (const vfloat4*)yhat, (const vfloat4*)y, yhat, y, partial, n4, n);
    l1_reduce_kernel<<<1, NTHREADS, 0, stream>>>(partial, out, inv_n);
}